// Round 3
// baseline (458.016 us; speedup 1.0000x reference)
//
#include <hip/hip_runtime.h>
#include <float.h>
#include <math.h>

// Problem constants (S=4096 tokens, E=64 experts, CAP=128)
#define SS 4096
#define EE 64
#define CAPC 128
#define ROW 8192                  // E*CAP floats per token per tensor
#define SEC (4096LL * 64 * 128)   // elements per [S,E,C] tensor
#define NGATE 256                 // gate blocks (16 tokens each)
#define TPB_TOK 16                // tokens per gate block
#define NFILL 4096                // fill blocks (16384 floats = 64 KB each)
#define NBLK_TOTAL (NGATE + NFILL)

// ---------------------------------------------------------------------------
// Single fused kernel (round-0 structure + last-block finish):
//   blocks [0,256):    gate for 16 tokens -> bc1/bc2/pg/tokmeta/tokg
//   blocks [256,4352): zero a contiguous 64 KB slice of out
//   all blocks:        __syncthreads (drain stores) -> __threadfence (release,
//                      L2 writeback for cross-XCD visibility) -> atomicAdd.
//   last-arriving block: acquire fence, in-place prefix scan over bc1/bc2,
//                      scatter all 4096 tokens' nonzeros, l_aux.
// FP summation orders identical to the passing 2-kernel version (absmax 0.0).
// ---------------------------------------------------------------------------
__global__ __launch_bounds__(256) void k_fused(
    const float* __restrict__ logits,
    const float* __restrict__ noise,
    int*   __restrict__ bc1,      // [256][64] counts -> overwritten with offsets
    int*   __restrict__ bc2,      // [256][64] counts -> overwritten with offsets
    float* __restrict__ pg,       // [256][64] per-block gate sums
    int*   __restrict__ tokmeta,  // [4096] packed idx/ranks
    float2* __restrict__ tokg,    // [4096] raw g1,g2
    int*   __restrict__ ctr,      // arrival counter (memset to 0 pre-launch)
    float* __restrict__ out)
{
    const int tid = threadIdx.x;
    const int b   = blockIdx.x;

    __shared__ int   s_idx1[TPB_TOK], s_idx2[TPB_TOK];
    __shared__ float s_gate[TPB_TOK][64];
    __shared__ int   s_part1[4][64], s_part2[4][64];
    __shared__ int   s_c1[64];
    __shared__ float s_gsL[64];
    __shared__ int   s_last;

    if (b >= NGATE) {
        // ---- pure fill block: zero floats [fb*16384, (fb+1)*16384) ----
        const int fb = blockIdx.x - NGATE;
        float4* p = (float4*)out + (long)fb * 4096;
        const float4 z = make_float4(0.f, 0.f, 0.f, 0.f);
        #pragma unroll
        for (int i = 0; i < 16; ++i) p[i * 256 + tid] = z;
        if (fb == NFILL - 1 && tid == 0) out[2 * SEC] = 0.f;  // last element
    } else {
        // ---- gate block: 4 waves, each handles 4 tokens ----
        const int wave = tid >> 6;
        const int lane = tid & 63;

        #pragma unroll
        for (int t4 = 0; t4 < 4; ++t4) {
            const int t = wave * 4 + t4;        // token within block
            const int s = b * TPB_TOK + t;
            const float l = logits[s * EE + lane];
            const float n = noise [s * EE + lane];

            // argmax over logits, first-index tie-break (all lanes agree)
            float v = l; int bi = lane;
            #pragma unroll
            for (int off = 32; off; off >>= 1) {
                float v2 = __shfl_xor(v, off, 64);
                int   i2 = __shfl_xor(bi, off, 64);
                if (v2 > v || (v2 == v && i2 < bi)) { v = v2; bi = i2; }
            }
            const int idx1 = bi;

            float e = expf(l - v);
            float sum = e;
            #pragma unroll
            for (int off = 32; off; off >>= 1) sum += __shfl_xor(sum, off, 64);
            const float gate = e / sum;

            // top-2 from logits+noise with top-1 masked to -FLT_MAX
            float lw = (lane == idx1) ? -FLT_MAX : (l + n);
            float v2v = lw; int bi2 = lane;
            #pragma unroll
            for (int off = 32; off; off >>= 1) {
                float q  = __shfl_xor(v2v, off, 64);
                int   i2 = __shfl_xor(bi2, off, 64);
                if (q > v2v || (q == v2v && i2 < bi2)) { v2v = q; bi2 = i2; }
            }
            const int idx2 = bi2;

            s_gate[t][lane] = gate;
            const float g1v = __shfl(gate, idx1, 64);
            const float g2v = __shfl(gate, idx2, 64);
            if (lane == 0) {
                s_idx1[t] = idx1;
                s_idx2[t] = idx2;
                tokg[s] = make_float2(g1v, g2v);
            }
        }
        __syncthreads();

        // per-block expert counts + gate sums, local ranks
        if (tid < 64) {
            int c1 = 0, c2 = 0;
            float gs = 0.f;
            #pragma unroll
            for (int j = 0; j < TPB_TOK; ++j) {
                c1 += (s_idx1[j] == tid);
                c2 += (s_idx2[j] == tid);
                gs += s_gate[j][tid];
            }
            bc1[b * 64 + tid] = c1;
            bc2[b * 64 + tid] = c2;
            pg [b * 64 + tid] = gs;
        } else if (tid < 64 + TPB_TOK) {
            const int t = tid - 64;
            const int m1 = s_idx1[t], m2 = s_idx2[t];
            int r1 = 0, r2 = 0;
            for (int j = 0; j < t; ++j) {
                r1 += (s_idx1[j] == m1);
                r2 += (s_idx2[j] == m2);
            }
            tokmeta[b * TPB_TOK + t] = m1 | (m2 << 6) | (r1 << 12) | (r2 << 17);
        }
    }

    // ---- arrival protocol ----
    __syncthreads();                  // drains all waves' stores to L2
    if (tid == 0) {
        __threadfence();              // release: L2 writeback (cross-XCD)
        const int old = atomicAdd(ctr, 1);
        s_last = (old == NBLK_TOTAL - 1) ? 1 : 0;
    }
    __syncthreads();
    if (!s_last) return;
    __threadfence();                  // acquire: invalidate stale local cache

    // =======================================================================
    // Last block: scan + scatter + l_aux (replaces the old K2 dispatch).
    // =======================================================================
    const int e = tid & 63;           // expert
    const int q = tid >> 6;           // quarter of the 256 gate blocks

    // pass 1: quarter partial sums of counts
    int p1 = 0, p2 = 0;
    {
        const int lo = q * 64, hi = lo + 64;
        #pragma unroll 8
        for (int blk = lo; blk < hi; ++blk) {
            p1 += bc1[blk * 64 + e];
            p2 += bc2[blk * 64 + e];
        }
        s_part1[q][e] = p1;
        s_part2[q][e] = p2;
    }
    __syncthreads();

    // quarter base offsets; totals for expert e
    int run1 = 0, run2 = 0;
    for (int qq = 0; qq < q; ++qq) { run1 += s_part1[qq][e]; run2 += s_part2[qq][e]; }
    if (q == 3) s_c1[e] = run1 + p1;

    // pass 2: in-place exclusive prefix — bc[blk][e] becomes offset of blk.
    // Each (blk,e) element is read+written by exactly one thread.
    {
        const int lo = q * 64, hi = lo + 64;
        for (int blk = lo; blk < hi; ++blk) {
            const int v1 = bc1[blk * 64 + e]; bc1[blk * 64 + e] = run1; run1 += v1;
            const int v2 = bc2[blk * 64 + e]; bc2[blk * 64 + e] = run2; run2 += v2;
        }
    }
    __syncthreads();                  // offsets + s_c1 ready

    // exact-order gate-sum totals (same FP order as the old K2)
    if (tid < 64) {
        float gs = 0.f;
        #pragma unroll 8
        for (int blk = 0; blk < NGATE; ++blk) gs += pg[blk * 64 + tid];
        s_gsL[tid] = gs;
    }

    // scatter: 16 tokens per thread
    float* combine = out + 1;
    float* mask    = out + 1 + SEC;
    for (int k = 0; k < 16; ++k) {
        const int s  = k * 256 + tid;
        const int gb = s >> 4;        // owning gate block
        const int m  = tokmeta[s];
        const int i1  =  m        & 63;
        const int i2  = (m >> 6)  & 63;
        const int lr1 = (m >> 12) & 31;
        const int lr2 = (m >> 17) & 31;
        const float2 g = tokg[s];
        const int loc1 = lr1 + bc1[gb * 64 + i1];
        const int loc2 = lr2 + bc2[gb * 64 + i2] + s_c1[i2];
        float g1 = g.x, g2 = g.y;
        const bool k1 = loc1 < CAPC, k2 = loc2 < CAPC;
        g1 = k1 ? g1 : 0.f;
        g2 = k2 ? g2 : 0.f;
        const float denom = fmaxf(g1 + g2, 1.1920929e-07f);  // finfo(f32).eps
        g1 /= denom;
        g2 /= denom;
        const long base = (long)s * ROW;
        if (k1 && g1 != 0.f) {
            const long p = base + (long)i1 * CAPC + loc1;
            combine[p] = g1;
            mask[p]    = 1.f;
        }
        if (k2 && g2 != 0.f) {
            const long p = base + (long)i2 * CAPC + loc2;
            combine[p] = g2;
            mask[p]    = 1.f;
        }
    }
    __syncthreads();                  // s_gsL complete

    if (tid == 0) {
        // l_aux = (E / S^2) * sum_e gs_e * cnt1_e  (same order as old K2)
        float prod = 0.f;
        #pragma unroll 8
        for (int ee = 0; ee < 64; ++ee) prod += s_gsL[ee] * (float)s_c1[ee];
        out[0] = prod * (float)EE / ((float)SS * (float)SS);
    }
}

// ---------------------------------------------------------------------------
// Launch: 4-byte counter memset + one fused kernel.
// ---------------------------------------------------------------------------
extern "C" void kernel_launch(void* const* d_in, const int* in_sizes, int n_in,
                              void* d_out, int out_size, void* d_ws, size_t ws_size,
                              hipStream_t stream) {
    const float* logits = (const float*)d_in[0];
    const float* noise  = (const float*)d_in[1];
    float* out = (float*)d_out;

    char* ws = (char*)d_ws;
    int*    bc1     = (int*)   (ws + 0);        // 64 KB
    int*    bc2     = (int*)   (ws + 65536);    // 64 KB
    float*  pg      = (float*) (ws + 131072);   // 64 KB
    int*    tokmeta = (int*)   (ws + 196608);   // 16 KB
    float2* tokg    = (float2*)(ws + 212992);   // 32 KB
    int*    ctr     = (int*)   (ws + 245760);   // 4 B arrival counter

    hipMemsetAsync(ctr, 0, 4, stream);
    k_fused<<<NBLK_TOTAL, 256, 0, stream>>>(logits, noise, bc1, bc2, pg,
                                            tokmeta, tokg, ctr, out);
}

// Round 4
// 319.227 us; speedup vs baseline: 1.4348x; 1.4348x over previous
//
#include <hip/hip_runtime.h>
#include <float.h>
#include <math.h>

// Problem constants (S=4096 tokens, E=64 experts, CAP=128)
#define SS 4096
#define EE 64
#define CAPC 128
#define ROW 8192                  // E*CAP floats per token per tensor
#define SEC (4096LL * 64 * 128)   // elements per [S,E,C] tensor
#define NGATE 256                 // gate blocks (16 tokens each)
#define TPB_TOK 16                // tokens per gate block
#define NFILLB 1024               // fill blocks (65536 floats = 256 KB each)
#define FPB 65536LL               // floats per fill block
#define GRID (NGATE + 1 + NFILLB) // 1281 blocks — all co-resident at 8 blk/CU

#define AQ  __HIP_MEMORY_SCOPE_AGENT
#define RLX __ATOMIC_RELAXED

// ---------------------------------------------------------------------------
// Single kernel, three roles by blockIdx (producers first):
//   [0,256):   gate — r0 math verbatim; metadata out via relaxed AGENT-scope
//              stores (MALL-coherent, no cache-maintenance ops); 1 atomicAdd.
//   256:       scan — spin ctr==256, r3-verified quarter prefix scan + token
//              drop/renorm math, emit tokrec[4096]{p1,p2,v1,v2} + l_aux,
//              drain, set flag.
//   [257,1281): fill 256 KB slice of out with plain float4 stores (bulk path
//              identical to r0), poll flag, patch own slice's <=36 candidate
//              entries in place (<=2 agent loads + 1 plain store each).
// No wbl2/invl2 anywhere (r3's killer); no coop launch (r1's killer); no
// second dispatch (r0's gap).  Co-residency of all 1281 blocks is guaranteed
// by __launch_bounds__(256,8) => spin cannot starve producers.
// FP orders for gate/renorm/l_aux identical to passed rounds (absmax 0.0).
// ---------------------------------------------------------------------------
__global__ __launch_bounds__(256, 8) void k_all(
    const float* __restrict__ logits,
    const float* __restrict__ noise,
    int*   __restrict__ bc1,      // [256][64] counts (agent-stored)
    int*   __restrict__ bc2,      // [256][64]
    float* __restrict__ pg,       // [256][64] gate sums
    int*   __restrict__ tokmeta,  // [4096] packed idx/ranks
    float2* __restrict__ tokg,    // [4096] raw g1,g2 (packed u64)
    int*   __restrict__ tokrec,   // [4096][4] p1,p2,v1bits,v2bits
    float* __restrict__ aux,      // l_aux scalar
    int*   __restrict__ ctr,      // gate arrival counter (memset 0)
    int*   __restrict__ flag,     // tokrec-ready flag   (memset 0)
    float* __restrict__ out)
{
    const int tid = threadIdx.x;
    const int b   = blockIdx.x;

    __shared__ int   s_idx1[TPB_TOK], s_idx2[TPB_TOK];
    __shared__ float s_gate[TPB_TOK][64];
    __shared__ int   s_part1[4][64], s_part2[4][64];
    __shared__ int   s_c1[64];
    __shared__ float s_gsL[64];

    if (b < NGATE) {
        // =================== gate block (r0 math verbatim) ===================
        const int wave = tid >> 6;
        const int lane = tid & 63;

        #pragma unroll
        for (int t4 = 0; t4 < 4; ++t4) {
            const int t = wave * 4 + t4;
            const int s = b * TPB_TOK + t;
            const float l = logits[s * EE + lane];
            const float n = noise [s * EE + lane];

            float v = l; int bi = lane;
            #pragma unroll
            for (int off = 32; off; off >>= 1) {
                float v2 = __shfl_xor(v, off, 64);
                int   i2 = __shfl_xor(bi, off, 64);
                if (v2 > v || (v2 == v && i2 < bi)) { v = v2; bi = i2; }
            }
            const int idx1 = bi;

            float e = expf(l - v);
            float sum = e;
            #pragma unroll
            for (int off = 32; off; off >>= 1) sum += __shfl_xor(sum, off, 64);
            const float gate = e / sum;

            float lw = (lane == idx1) ? -FLT_MAX : (l + n);
            float v2v = lw; int bi2 = lane;
            #pragma unroll
            for (int off = 32; off; off >>= 1) {
                float q  = __shfl_xor(v2v, off, 64);
                int   i2 = __shfl_xor(bi2, off, 64);
                if (q > v2v || (q == v2v && i2 < bi2)) { v2v = q; bi2 = i2; }
            }
            const int idx2 = bi2;

            s_gate[t][lane] = gate;
            const float g1v = __shfl(gate, idx1, 64);
            const float g2v = __shfl(gate, idx2, 64);
            if (lane == 0) {
                s_idx1[t] = idx1;
                s_idx2[t] = idx2;
                unsigned long long pk = (unsigned long long)__float_as_uint(g1v)
                    | ((unsigned long long)__float_as_uint(g2v) << 32);
                __hip_atomic_store((unsigned long long*)&tokg[s], pk, RLX, AQ);
            }
        }
        __syncthreads();

        if (tid < 64) {
            int c1 = 0, c2 = 0;
            float gs = 0.f;
            #pragma unroll
            for (int j = 0; j < TPB_TOK; ++j) {
                c1 += (s_idx1[j] == tid);
                c2 += (s_idx2[j] == tid);
                gs += s_gate[j][tid];
            }
            __hip_atomic_store(&bc1[b * 64 + tid], c1, RLX, AQ);
            __hip_atomic_store(&bc2[b * 64 + tid], c2, RLX, AQ);
            __hip_atomic_store(&pg [b * 64 + tid], gs, RLX, AQ);
        } else if (tid < 64 + TPB_TOK) {
            const int t = tid - 64;
            const int m1 = s_idx1[t], m2 = s_idx2[t];
            int r1 = 0, r2 = 0;
            for (int j = 0; j < t; ++j) {
                r1 += (s_idx1[j] == m1);
                r2 += (s_idx2[j] == m2);
            }
            __hip_atomic_store(&tokmeta[b * TPB_TOK + t],
                               m1 | (m2 << 6) | (r1 << 12) | (r2 << 17), RLX, AQ);
        }
        __syncthreads();                       // drains all waves' stores
        if (tid == 0) {
            asm volatile("s_waitcnt vmcnt(0)" ::: "memory");
            __hip_atomic_fetch_add(ctr, 1, RLX, AQ);
        }
        return;
    }

    if (b == NGATE) {
        // =================== scan block (r3-verified logic) ==================
        if (tid == 0) {
            while (__hip_atomic_load(ctr, RLX, AQ) < NGATE)
                __builtin_amdgcn_s_sleep(2);
        }
        __syncthreads();

        const int e = tid & 63;
        const int q = tid >> 6;

        // pass 1: quarter partial sums of counts
        int p1 = 0, p2 = 0;
        {
            const int lo = q * 64, hi = lo + 64;
            #pragma unroll 8
            for (int blk = lo; blk < hi; ++blk) {
                p1 += bc1[blk * 64 + e];
                p2 += bc2[blk * 64 + e];
            }
            s_part1[q][e] = p1;
            s_part2[q][e] = p2;
        }
        __syncthreads();

        int run1 = 0, run2 = 0;
        for (int qq = 0; qq < q; ++qq) { run1 += s_part1[qq][e]; run2 += s_part2[qq][e]; }
        if (q == 3) s_c1[e] = run1 + p1;

        // pass 2: in-place exclusive prefix (single owner per element)
        {
            const int lo = q * 64, hi = lo + 64;
            for (int blk = lo; blk < hi; ++blk) {
                const int v1 = bc1[blk * 64 + e]; bc1[blk * 64 + e] = run1; run1 += v1;
                const int v2 = bc2[blk * 64 + e]; bc2[blk * 64 + e] = run2; run2 += v2;
            }
        }
        __syncthreads();                  // offsets + s_c1 ready

        // exact-order gate-sum totals (same FP order as r0's K2)
        if (tid < 64) {
            float gs = 0.f;
            #pragma unroll 8
            for (int blk = 0; blk < NGATE; ++blk) gs += pg[blk * 64 + tid];
            s_gsL[tid] = gs;
        }

        // tokrec build: 16 tokens per thread (drop/renorm verbatim)
        #pragma unroll 4
        for (int k = 0; k < 16; ++k) {
            const int s  = k * 256 + tid;
            const int gb = s >> 4;
            const int m  = __hip_atomic_load(&tokmeta[s], RLX, AQ);
            const unsigned long long pk =
                __hip_atomic_load((unsigned long long*)&tokg[s], RLX, AQ);
            const float gx = __uint_as_float((unsigned)(pk & 0xffffffffu));
            const float gy = __uint_as_float((unsigned)(pk >> 32));
            const int i1  =  m        & 63;
            const int i2  = (m >> 6)  & 63;
            const int lr1 = (m >> 12) & 31;
            const int lr2 = (m >> 17) & 31;
            const int loc1 = lr1 + bc1[gb * 64 + i1];
            const int loc2 = lr2 + bc2[gb * 64 + i2] + s_c1[i2];
            float g1 = gx, g2 = gy;
            const bool k1 = loc1 < CAPC, k2 = loc2 < CAPC;
            g1 = k1 ? g1 : 0.f;
            g2 = k2 ? g2 : 0.f;
            const float denom = fmaxf(g1 + g2, 1.1920929e-07f);
            g1 /= denom;
            g2 /= denom;
            const int pp1 = (k1 && g1 != 0.f) ? (i1 * CAPC + loc1) : -1;
            const int pp2 = (k2 && g2 != 0.f) ? (i2 * CAPC + loc2) : -1;
            __hip_atomic_store(&tokrec[s * 4 + 0], pp1, RLX, AQ);
            __hip_atomic_store(&tokrec[s * 4 + 1], pp2, RLX, AQ);
            __hip_atomic_store(&tokrec[s * 4 + 2], __float_as_int(g1), RLX, AQ);
            __hip_atomic_store(&tokrec[s * 4 + 3], __float_as_int(g2), RLX, AQ);
        }
        __syncthreads();                  // s_gsL complete

        if (tid == 0) {
            float prod = 0.f;
            #pragma unroll 8
            for (int ee = 0; ee < 64; ++ee) prod += s_gsL[ee] * (float)s_c1[ee];
            __hip_atomic_store(aux, prod * (float)EE / ((float)SS * (float)SS),
                               RLX, AQ);
        }
        __syncthreads();                  // drains every wave's agent stores
        if (tid == 0) {
            asm volatile("s_waitcnt vmcnt(0)" ::: "memory");
            __hip_atomic_store(flag, 1, RLX, AQ);
        }
        return;
    }

    // ======================= fill + patch block ==========================
    const int  fb = b - NGATE - 1;             // [0, 1024)
    const long L  = (long)fb * FPB;

    // bulk zero: 256 KB contiguous, plain float4 stores (r0 BW path)
    {
        float4* p = (float4*)out + (long)fb * (FPB / 4);
        const float4 z = make_float4(0.f, 0.f, 0.f, 0.f);
        #pragma unroll
        for (int i = 0; i < 64; ++i) p[i * 256 + tid] = z;
        if (fb == NFILLB - 1 && tid == 0) out[2 * SEC] = 0.f;  // last element
    }
    __syncthreads();                      // zero stores drained

    if (tid == 0) {
        while (__hip_atomic_load(flag, RLX, AQ) == 0)
            __builtin_amdgcn_s_sleep(2);
    }
    __syncthreads();                      // flag observed by all

    // patch: candidate (tensor, row-slot, entry) triples intersecting slice
    if (tid < 36) {
        const int  tensor = tid / 18;     // 0=combine, 1=mask
        const int  r      = tid % 18;
        const int  slot   = r >> 1;       // 0..8
        const int  which  = r & 1;        // entry 1 or 2
        const long B      = 1 + (long)tensor * SEC;
        const int  s_lo   = (int)((L - B) >> 13);   // floor((L-B)/8192)
        const int  s      = s_lo + slot;
        if (s >= 0 && s < SS) {
            const int pp = __hip_atomic_load(&tokrec[s * 4 + which], RLX, AQ);
            if (pp >= 0) {
                const long g   = B + (long)s * ROW + pp;
                const long lim = L + FPB + (fb == NFILLB - 1 ? 1 : 0);
                if (g >= L && g < lim) {
                    float v = 1.f;
                    if (tensor == 0) {
                        const int vb =
                            __hip_atomic_load(&tokrec[s * 4 + 2 + which], RLX, AQ);
                        v = __int_as_float(vb);
                    }
                    out[g] = v;           // plain store into own zeroed slice
                }
            }
        }
    } else if (tid == 36 && fb == 0) {
        out[0] = __hip_atomic_load(aux, RLX, AQ);   // l_aux
    }
}

// ---------------------------------------------------------------------------
// Launch: 8-byte {ctr,flag} memset + one kernel.
// ---------------------------------------------------------------------------
extern "C" void kernel_launch(void* const* d_in, const int* in_sizes, int n_in,
                              void* d_out, int out_size, void* d_ws, size_t ws_size,
                              hipStream_t stream) {
    const float* logits = (const float*)d_in[0];
    const float* noise  = (const float*)d_in[1];
    float* out = (float*)d_out;

    char* ws = (char*)d_ws;
    int*    bc1     = (int*)   (ws + 0);        // 64 KB
    int*    bc2     = (int*)   (ws + 65536);    // 64 KB
    float*  pg      = (float*) (ws + 131072);   // 64 KB
    int*    tokmeta = (int*)   (ws + 196608);   // 16 KB
    float2* tokg    = (float2*)(ws + 212992);   // 32 KB
    int*    tokrec  = (int*)   (ws + 245760);   // 64 KB
    float*  aux     = (float*) (ws + 311296);   // 4 B
    int*    ctr     = (int*)   (ws + 311300);   // 4 B
    int*    flag    = (int*)   (ws + 311304);   // 4 B

    hipMemsetAsync(ws + 311300, 0, 8, stream);  // ctr + flag
    k_all<<<GRID, 256, 0, stream>>>(logits, noise, bc1, bc2, pg, tokmeta, tokg,
                                    tokrec, aux, ctr, flag, out);
}

// Round 5
// 268.801 us; speedup vs baseline: 1.7039x; 1.1876x over previous
//
#include <hip/hip_runtime.h>
#include <float.h>
#include <math.h>

// Problem constants (S=4096 tokens, E=64 experts, CAP=128)
#define SS 4096
#define EE 64
#define CAPC 128
#define ROW 8192                  // E*CAP floats per token per tensor
#define SEC (4096LL * 64 * 128)   // elements per [S,E,C] tensor
#define NGATE 256                 // gate blocks (16 tokens each)
#define NFILL 4096                // fill blocks (16384 floats = 64 KB each)
#define TPB_TOK 16                // tokens per gate block

// ---------------------------------------------------------------------------
// K1: fused gate + fill (round-0 structure — measured best at 272.5 us).
//   blocks [0, 256):    gate for 16 tokens (4 waves x 4 tokens), local ranks,
//                       per-block expert counts / gate sums -> ws only.
//   blocks [256, 4352): pure fill — zero a contiguous 64 KB slice of out.
// Gate work (~5us) hides under the fill (~41us).
// Change vs r0: bc1/bc2/pg stored TRANSPOSED as [64 experts][256 blocks] so
// K2's scan reads each expert's 256 counts as 64 contiguous int4 loads
// (was 256 stride-256B dword loads on the scatter critical path).
// ---------------------------------------------------------------------------
__global__ __launch_bounds__(256) void k1_gate_fill(
    const float* __restrict__ logits,
    const float* __restrict__ noise,
    int*   __restrict__ bc1,      // [64][256] per-block top1 counts (transposed)
    int*   __restrict__ bc2,      // [64][256] per-block top2 counts (transposed)
    float* __restrict__ pg,       // [64][256] per-block gate sums   (transposed)
    int*   __restrict__ tokmeta,  // [4096] packed idx/ranks
    float2* __restrict__ tokg,    // [4096] raw g1,g2
    float* __restrict__ out)
{
    const int tid = threadIdx.x;

    if (blockIdx.x >= NGATE) {
        // ---- pure fill block: zero floats [fb*16384, (fb+1)*16384) ----
        const int fb = blockIdx.x - NGATE;
        float4* p = (float4*)out + (long)fb * 4096;
        const float4 z = make_float4(0.f, 0.f, 0.f, 0.f);
        #pragma unroll
        for (int i = 0; i < 16; ++i) p[i * 256 + tid] = z;
        if (fb == NFILL - 1 && tid == 0) out[2 * SEC] = 0.f;  // last element
        return;
    }

    // ---- gate block: 4 waves, each handles 4 tokens ----
    const int b    = blockIdx.x;
    const int wave = tid >> 6;
    const int lane = tid & 63;

    __shared__ int   s_idx1[TPB_TOK], s_idx2[TPB_TOK];
    __shared__ float s_gate[TPB_TOK][64];

    #pragma unroll
    for (int t4 = 0; t4 < 4; ++t4) {
        const int t = wave * 4 + t4;        // token within block
        const int s = b * TPB_TOK + t;
        const float l = logits[s * EE + lane];
        const float n = noise [s * EE + lane];

        // argmax over logits, first-index tie-break (all lanes agree)
        float v = l; int bi = lane;
        #pragma unroll
        for (int off = 32; off; off >>= 1) {
            float v2 = __shfl_xor(v, off, 64);
            int   i2 = __shfl_xor(bi, off, 64);
            if (v2 > v || (v2 == v && i2 < bi)) { v = v2; bi = i2; }
        }
        const int idx1 = bi;

        float e = expf(l - v);
        float sum = e;
        #pragma unroll
        for (int off = 32; off; off >>= 1) sum += __shfl_xor(sum, off, 64);
        const float gate = e / sum;

        // top-2 from logits+noise with top-1 masked to -FLT_MAX
        float lw = (lane == idx1) ? -FLT_MAX : (l + n);
        float v2v = lw; int bi2 = lane;
        #pragma unroll
        for (int off = 32; off; off >>= 1) {
            float q  = __shfl_xor(v2v, off, 64);
            int   i2 = __shfl_xor(bi2, off, 64);
            if (q > v2v || (q == v2v && i2 < bi2)) { v2v = q; bi2 = i2; }
        }
        const int idx2 = bi2;

        s_gate[t][lane] = gate;
        const float g1v = __shfl(gate, idx1, 64);
        const float g2v = __shfl(gate, idx2, 64);
        if (lane == 0) {
            s_idx1[t] = idx1;
            s_idx2[t] = idx2;
            tokg[s] = make_float2(g1v, g2v);
        }
    }
    __syncthreads();

    // ---- per-block expert counts + gate sums (transposed layout), ranks ----
    if (tid < 64) {
        int c1 = 0, c2 = 0;
        float gs = 0.f;
        #pragma unroll
        for (int j = 0; j < TPB_TOK; ++j) {
            c1 += (s_idx1[j] == tid);
            c2 += (s_idx2[j] == tid);
            gs += s_gate[j][tid];
        }
        bc1[tid * NGATE + b] = c1;
        bc2[tid * NGATE + b] = c2;
        pg [tid * NGATE + b] = gs;
    } else if (tid < 64 + TPB_TOK) {
        const int t = tid - 64;
        const int m1 = s_idx1[t], m2 = s_idx2[t];
        int r1 = 0, r2 = 0;
        for (int j = 0; j < t; ++j) {
            r1 += (s_idx1[j] == m1);
            r2 += (s_idx2[j] == m2);
        }
        tokmeta[b * TPB_TOK + t] = m1 | (m2 << 6) | (r1 << 12) | (r2 << 17);
    }
}

// ---------------------------------------------------------------------------
// K2: redundant per-block prefix scan (transposed, contiguous int4 loads,
// L2-resident) + scatter of this block's 16 tokens.  Block 0 also computes
// l_aux.  256 blocks x 256 threads.  Stream order guarantees out is zeroed.
// ---------------------------------------------------------------------------
__global__ __launch_bounds__(256) void k2_scan_scatter(
    const int*   __restrict__ bc1,
    const int*   __restrict__ bc2,
    const float* __restrict__ pg,
    const int*   __restrict__ tokmeta,
    const float2* __restrict__ tokg,
    float* __restrict__ out)
{
    const int tid = threadIdx.x;
    const int b   = blockIdx.x;

    __shared__ int   s_off1[64], s_off2[64], s_cnt1[64];
    __shared__ float s_gs[64];

    if (tid < 64) {
        // exclusive prefix of bc1 over blocks, capture own offset + total
        const int4* row = (const int4*)(bc1 + tid * NGATE);
        int o1 = 0, mine = 0;
        #pragma unroll 16
        for (int j = 0; j < 64; ++j) {
            const int4 v = row[j];
            const int blk = j * 4;
            if (blk + 0 == b) mine = o1;
            o1 += v.x;
            if (blk + 1 == b) mine = o1;
            o1 += v.y;
            if (blk + 2 == b) mine = o1;
            o1 += v.z;
            if (blk + 3 == b) mine = o1;
            o1 += v.w;
        }
        s_off1[tid] = mine;
        s_cnt1[tid] = o1;
    } else if (tid < 128) {
        const int e = tid - 64;
        const int4* row = (const int4*)(bc2 + e * NGATE);
        int o2 = 0, mine = 0;
        #pragma unroll 16
        for (int j = 0; j < 64; ++j) {
            const int4 v = row[j];
            const int blk = j * 4;
            if (blk + 0 == b) mine = o2;
            o2 += v.x;
            if (blk + 1 == b) mine = o2;
            o2 += v.y;
            if (blk + 2 == b) mine = o2;
            o2 += v.z;
            if (blk + 3 == b) mine = o2;
            o2 += v.w;
        }
        s_off2[e] = mine;
    } else if (tid < 192 && b == 0) {
        // gate-sum totals; add order blk=0..255 identical to scalar version
        const int e = tid - 128;
        const float4* row = (const float4*)(pg + e * NGATE);
        float gs = 0.f;
        #pragma unroll 16
        for (int j = 0; j < 64; ++j) {
            const float4 v = row[j];
            gs += v.x;
            gs += v.y;
            gs += v.z;
            gs += v.w;
        }
        s_gs[e] = gs;
    }
    __syncthreads();

    if (tid < TPB_TOK) {
        const int s = b * TPB_TOK + tid;
        const int m = tokmeta[s];
        const int i1  =  m        & 63;
        const int i2  = (m >> 6)  & 63;
        const int lr1 = (m >> 12) & 31;
        const int lr2 = (m >> 17) & 31;
        const float2 g = tokg[s];
        const int loc1 = lr1 + s_off1[i1];
        const int loc2 = lr2 + s_off2[i2] + s_cnt1[i2];
        float g1 = g.x, g2 = g.y;
        const bool k1 = loc1 < CAPC, k2 = loc2 < CAPC;
        g1 = k1 ? g1 : 0.f;
        g2 = k2 ? g2 : 0.f;
        const float denom = fmaxf(g1 + g2, 1.1920929e-07f);  // finfo(f32).eps
        g1 /= denom;
        g2 /= denom;
        float* combine = out + 1;
        float* mask    = out + 1 + SEC;
        const long base = (long)s * ROW;
        if (k1 && g1 != 0.f) {
            const long p = base + (long)i1 * CAPC + loc1;
            combine[p] = g1;
            mask[p]    = 1.f;
        }
        if (k2 && g2 != 0.f) {
            const long p = base + (long)i2 * CAPC + loc2;
            combine[p] = g2;
            mask[p]    = 1.f;
        }
    } else if (tid == 64 + TPB_TOK && b == 0) {
        // l_aux = (E / S^2) * sum_e gs_e * cnt1_e
        float prod = 0.f;
        #pragma unroll 8
        for (int e = 0; e < 64; ++e) prod += s_gs[e] * (float)s_cnt1[e];
        out[0] = prod * (float)EE / ((float)SS * (float)SS);
    }
}

// ---------------------------------------------------------------------------
// Launch: fused gate+fill -> scan+scatter.  Plain sequential dispatches —
// r1 (cooperative), r3 (device fences), r4 (spin-flag) all measured SLOWER
// than this two-dispatch structure; do not revisit intra-kernel sync.
// ---------------------------------------------------------------------------
extern "C" void kernel_launch(void* const* d_in, const int* in_sizes, int n_in,
                              void* d_out, int out_size, void* d_ws, size_t ws_size,
                              hipStream_t stream) {
    const float* logits = (const float*)d_in[0];
    const float* noise  = (const float*)d_in[1];
    float* out = (float*)d_out;

    char* ws = (char*)d_ws;
    int*    bc1     = (int*)   (ws + 0);        // 64 KB  [64][256]
    int*    bc2     = (int*)   (ws + 65536);    // 64 KB  [64][256]
    float*  pg      = (float*) (ws + 131072);   // 64 KB  [64][256]
    int*    tokmeta = (int*)   (ws + 196608);   // 16 KB
    float2* tokg    = (float2*)(ws + 212992);   // 32 KB

    k1_gate_fill<<<NGATE + NFILL, 256, 0, stream>>>(logits, noise, bc1, bc2, pg,
                                                    tokmeta, tokg, out);
    k2_scan_scatter<<<NGATE, 256, 0, stream>>>(bc1, bc2, pg, tokmeta, tokg, out);
}